// Round 4
// baseline (331.670 us; speedup 1.0000x reference)
//
#include <hip/hip_runtime.h>
#include <stdint.h>

#define NN 32768
#define DEG 16
#define CH 128
#define G4 512
#define MB 128         // nodes per LSTM block (8 mt tiles)
#define BUF 32768      // byte stride between the two h buffers

typedef short bf16x8 __attribute__((ext_vector_type(8)));
typedef float f32x4 __attribute__((ext_vector_type(4)));
typedef unsigned short u16;
typedef u16 u16x8 __attribute__((ext_vector_type(8)));
typedef uint32_t u32;

#define L2E  1.4426950408889634f
#define L2E2 2.8853900817779268f

__device__ __forceinline__ u16 f2bf(float f) {
  union { float f; uint32_t u; } v; v.f = f;
  uint32_t u = v.u;
  return (u16)((u + 0x7FFFu + ((u >> 16) & 1u)) >> 16);
}
__device__ __forceinline__ float exp2f_fast(float x) {
#if __has_builtin(__builtin_amdgcn_exp2f)
  return __builtin_amdgcn_exp2f(x);
#else
  float r; asm("v_exp_f32 %0, %1" : "=v"(r) : "v"(x)); return r;
#endif
}
__device__ __forceinline__ float rcpf_fast(float x) {
#if __has_builtin(__builtin_amdgcn_rcpf)
  return __builtin_amdgcn_rcpf(x);
#else
  float r; asm("v_rcp_f32 %0, %1" : "=v"(r) : "v"(x)); return r;
#endif
}
__device__ __forceinline__ u32 cvtpk(float lo, float hi) {
  u32 r; asm("v_cvt_pk_bf16_f32 %0, %1, %2" : "=v"(r) : "v"(lo), "v"(hi));
  return r;
}

// ---------------- prep kernels ----------------
__global__ void k_cvt_bf16(const float* __restrict__ in, u16* __restrict__ out, int n8) {
  int i = blockIdx.x * blockDim.x + threadIdx.x;
  if (i >= n8) return;
  const float* pp = in + (size_t)i * 8;
  u16x8 o;
  #pragma unroll
  for (int j = 0; j < 8; ++j) o[j] = f2bf(pp[j]);
  *(u16x8*)(out + (size_t)i * 8) = o;
}

// weights/bias pre-scaled by log2e (2*log2e for gate g)
__global__ void k_pack_lstm(const float* __restrict__ wih, const float* __restrict__ whh,
                            const float* __restrict__ bih, const float* __restrict__ bhh,
                            u16* __restrict__ Wc, float* __restrict__ bs) {
  int idx = blockIdx.x * blockDim.x + threadIdx.x;   // 512*256
  int g = idx >> 8, k = idx & 255;
  int gate = g >> 7;
  float sc = (gate == 2) ? L2E2 : L2E;
  float v = (k < CH) ? wih[g * CH + k] : whh[g * CH + (k - CH)];
  Wc[g * 256 + k] = f2bf(v * sc);
  if (k == 0) bs[g] = (bih[g] + bhh[g]) * sc;
}

__global__ void k_pack_lin(const float* __restrict__ wl, const float* __restrict__ wr,
                           u16* __restrict__ W) {
  int idx = blockIdx.x * blockDim.x + threadIdx.x;   // 128*256
  int o = idx >> 8, k = idx & 255;
  float v = (k < CH) ? wl[o * CH + k] : wr[o * CH + (k - CH)];
  W[o * 256 + k] = f2bf(v);
}

// ---------------- Gx = x @ wih.T (pre-scaled), stored [node][c][gate] bf16 ----------------
// block: 512 thr, 64 nodes x all 512 gate-cols; wave w owns j-tiles 4w..4w+3.
__global__ __launch_bounds__(512, 2)
void k_gates(const u16* __restrict__ xin, const u16* __restrict__ Wc,
             u16* __restrict__ gx) {
  const int lane = threadIdx.x & 63;
  const int wave = threadIdx.x >> 6;
  const int l15 = lane & 15, lg = lane >> 4;
  const int nodeBase = blockIdx.x * 64;

  // B-frags: out-col j=(wave*4+ct)*16+l15 -> wih row (j&3)*128 + (j>>2), k in [0,128)
  bf16x8 B[4][4];
  int cb[4];
  #pragma unroll
  for (int ct = 0; ct < 4; ++ct) {
    int j = (wave * 4 + ct) * 16 + l15;
    int wr = ((j & 3) << 7) + (j >> 2);
    cb[ct] = (j >> 2) * 8 + (j & 3) * 2;   // byte offset within node's 1024B row
    #pragma unroll
    for (int kt = 0; kt < 4; ++kt)
      B[ct][kt] = *(const bf16x8*)(Wc + wr * 256 + kt * 32 + lg * 8);
  }
  char* gxc = (char*)gx;
  const f32x4 zero4 = {0.f, 0.f, 0.f, 0.f};
  #pragma unroll
  for (int mt = 0; mt < 4; ++mt) {
    bf16x8 A[4];
    #pragma unroll
    for (int kt = 0; kt < 4; ++kt)
      A[kt] = *(const bf16x8*)(xin + (size_t)(nodeBase + mt * 16 + l15) * CH + kt * 32 + lg * 8);
    f32x4 acc[4] = { zero4, zero4, zero4, zero4 };
    #pragma unroll
    for (int kt = 0; kt < 4; ++kt)
      #pragma unroll
      for (int ct = 0; ct < 4; ++ct)
        acc[ct] = __builtin_amdgcn_mfma_f32_16x16x32_bf16(A[kt], B[ct][kt], acc[ct], 0, 0, 0);
    #pragma unroll
    for (int ct = 0; ct < 4; ++ct)
      #pragma unroll
      for (int q = 0; q < 4; ++q)
        *(u16*)(gxc + (size_t)(nodeBase + mt * 16 + lg * 4 + q) * 1024 + cb[ct]) =
            f2bf(acc[ct][q]);
  }
}

// ---------------- LSTM aggregation (recurrent part only: h @ whh.T) ----------------
// 512 thr = 8 waves, 128 nodes/block, grid 256 (1 block/CU, single shot).
// LDS: h double-buffer 2x32KB (swizzled) + srcsT 8KB. Gx gathered per step
// from global (L3-resident) with depth-3 mt prefetch pipeline.
#define GXISSUE(m) do {                                                        \
    int4 sv_ = *(const int4*)(ldsc + sTr + (m) * 64);                          \
    gq[m][0] = *(const uint2*)(gxb + (((u32)sv_.x << 10) + gxoff));            \
    gq[m][1] = *(const uint2*)(gxb + (((u32)sv_.y << 10) + gxoff));            \
    gq[m][2] = *(const uint2*)(gxb + (((u32)sv_.z << 10) + gxoff));            \
    gq[m][3] = *(const uint2*)(gxb + (((u32)sv_.w << 10) + gxoff));            \
  } while (0)

__global__ __launch_bounds__(512, 2)
void k_lstm(const u16* __restrict__ gx, const int* __restrict__ src,
            const u16* __restrict__ Wc, const float* __restrict__ bs,
            u16* __restrict__ aggr) {
  __shared__ char lds[2 * 32768 + 8192];  // h dbuf (swizzled) + srcsT[t][128]
  char* ldsc = lds;
  const int tid = threadIdx.x;
  const int lane = tid & 63;
  const int wave = tid >> 6;
  const int l15 = lane & 15;
  const int lg  = lane >> 4;
  const int nodeBase = blockIdx.x * MB;

  // stage srcsT[t][row] (transposed) once
  {
    int row = tid >> 2, tq = (tid & 3) * 4;
    int4 s4 = *(const int4*)(src + (size_t)(nodeBase + row) * DEG + tq);
    int b = 65536 + row * 4;
    *(int*)(ldsc + b + (tq + 0) * 512) = s4.x;
    *(int*)(ldsc + b + (tq + 1) * 512) = s4.y;
    *(int*)(ldsc + b + (tq + 2) * 512) = s4.z;
    *(int*)(ldsc + b + (tq + 3) * 512) = s4.w;
  }
  // zero h buffer 0
  {
    int4 z = {0, 0, 0, 0};
    #pragma unroll
    for (int j = 0; j < 4; ++j) *(int4*)(ldsc + tid * 64 + j * 16) = z;
  }

  // weight B-frags (whh half, pre-scaled): row = gate*128 + wave*16 + l15, k in [128,256)
  bf16x8 Wf[4][4];
  {
    const u16* wp = Wc + (wave * 16 + l15) * 256 + 128 + lg * 8;
    #pragma unroll
    for (int gt = 0; gt < 4; ++gt)
      #pragma unroll
      for (int kt = 0; kt < 4; ++kt)
        Wf[gt][kt] = *(const bf16x8*)(wp + gt * (CH * 256) + kt * 32);
  }
  f32x4 bias[4];
  #pragma unroll
  for (int gt = 0; gt < 4; ++gt) {
    float b = bs[gt * CH + wave * 16 + l15];
    bias[gt] = { b, b, b, b };
  }

  // hoisted addresses. h row stride 256B; swizzle: byte col ^= (row&7)<<4
  int aAr = l15 * 256 + ((lg * 16) ^ ((l15 & 7) << 4));  // + mt*4096 + {0,128}
  int aBr = aAr ^ 64;
  const int hcol = (wave * 16 + l15) * 2;
  int hw0 = (lg * 4 + 0) * 256 + (hcol ^ ((((lg * 4) + 0) & 7) << 4)) + BUF;
  int hw1 = (lg * 4 + 1) * 256 + (hcol ^ ((((lg * 4) + 1) & 7) << 4)) + BUF;
  int hw2 = (lg * 4 + 2) * 256 + (hcol ^ ((((lg * 4) + 2) & 7) << 4)) + BUF;
  int hw3 = (lg * 4 + 3) * 256 + (hcol ^ ((((lg * 4) + 3) & 7) << 4)) + BUF;
  int sTr = 65536 + lg * 16;                    // srcsT row base, += 512 per step
  const u32 gxoff = (u32)(wave * 16 + l15) * 8;
  const char* gxb = (const char*)gx;
  u16* aggrp = aggr + (size_t)(nodeBase + lg * 4) * CH + wave * 16 + l15;

  float cst[8][4] = {{0.f}};
  f32x4 acc[2][4];

  __syncthreads();                   // srcsT + zeroed h visible

  #pragma unroll 1
  for (int t = 0; t < DEG; ++t) {
    __syncthreads();                 // h(t-1) writes visible
    uint2 gq[8][4];
    GXISSUE(0); GXISSUE(1); GXISSUE(2);
    #pragma unroll
    for (int mt = 0; mt < 8; ++mt) {
      const int pp = mt & 1;
      if (mt < 5) GXISSUE(mt + 3);
      __builtin_amdgcn_s_setprio(1);
      {
        const bf16x8 A0 = *(const bf16x8*)(ldsc + aAr + mt * 4096);
        const bf16x8 A1 = *(const bf16x8*)(ldsc + aBr + mt * 4096);
        const bf16x8 A2 = *(const bf16x8*)(ldsc + aAr + mt * 4096 + 128);
        const bf16x8 A3 = *(const bf16x8*)(ldsc + aBr + mt * 4096 + 128);
        #pragma unroll
        for (int gt = 0; gt < 4; ++gt)
          acc[pp][gt] = __builtin_amdgcn_mfma_f32_16x16x32_bf16(A0, Wf[gt][0], bias[gt], 0, 0, 0);
        #pragma unroll
        for (int gt = 0; gt < 4; ++gt)
          acc[pp][gt] = __builtin_amdgcn_mfma_f32_16x16x32_bf16(A1, Wf[gt][1], acc[pp][gt], 0, 0, 0);
        #pragma unroll
        for (int gt = 0; gt < 4; ++gt)
          acc[pp][gt] = __builtin_amdgcn_mfma_f32_16x16x32_bf16(A2, Wf[gt][2], acc[pp][gt], 0, 0, 0);
        #pragma unroll
        for (int gt = 0; gt < 4; ++gt)
          acc[pp][gt] = __builtin_amdgcn_mfma_f32_16x16x32_bf16(A3, Wf[gt][3], acc[pp][gt], 0, 0, 0);
      }
      __builtin_amdgcn_s_setprio(0);
      float hq[4];
      #pragma unroll
      for (int q = 0; q < 4; ++q) {
        float xi = __uint_as_float(gq[mt][q].x << 16);
        float xf = __uint_as_float(gq[mt][q].x & 0xFFFF0000u);
        float xg = __uint_as_float(gq[mt][q].y << 16);
        float xo = __uint_as_float(gq[mt][q].y & 0xFFFF0000u);
        float p0 = acc[pp][0][q] + xi;
        float p1 = acc[pp][1][q] + xf;
        float p2 = acc[pp][2][q] + xg;
        float p3 = acc[pp][3][q] + xo;
        float si = rcpf_fast(1.0f + exp2f_fast(-p0));
        float sf = rcpf_fast(1.0f + exp2f_fast(-p1));
        float so = rcpf_fast(1.0f + exp2f_fast(-p3));
        float gg = fmaf(-2.0f, rcpf_fast(1.0f + exp2f_fast(p2)), 1.0f);
        float c  = fmaf(sf, cst[mt][q], si * gg);
        cst[mt][q] = c;
        float tc = fmaf(-2.0f, rcpf_fast(1.0f + exp2f_fast(c * L2E2)), 1.0f);
        hq[q] = so * tc;
      }
      u32 hp0 = cvtpk(hq[0], hq[1]);
      u32 hp1 = cvtpk(hq[2], hq[3]);
      if (t != DEG - 1) {
        *(u16*)(ldsc + hw0 + mt * 4096) = (u16)hp0;
        *(u16*)(ldsc + hw1 + mt * 4096) = (u16)(hp0 >> 16);
        *(u16*)(ldsc + hw2 + mt * 4096) = (u16)hp1;
        *(u16*)(ldsc + hw3 + mt * 4096) = (u16)(hp1 >> 16);
      } else {
        u16* op_ = aggrp + mt * 16 * CH;
        op_[0 * CH] = (u16)hp0;
        op_[1 * CH] = (u16)(hp0 >> 16);
        op_[2 * CH] = (u16)hp1;
        op_[3 * CH] = (u16)(hp1 >> 16);
      }
    }
    aAr ^= BUF; aBr ^= BUF;
    hw0 ^= BUF; hw1 ^= BUF; hw2 ^= BUF; hw3 ^= BUF;
    sTr += 512;
  }
}

// ---------------- fused lin_l/lin_r ----------------
__global__ __launch_bounds__(256, 4)
void k_linear(const u16* __restrict__ aggr, const u16* __restrict__ xroot,
              const u16* __restrict__ W, const float* __restrict__ bl,
              u16* __restrict__ out_bf, float* __restrict__ out_f, int relu) {
  const int lane = threadIdx.x & 63;
  const int wave = threadIdx.x >> 6;
  const int l15 = lane & 15, lg = lane >> 4;
  const int rowBase = blockIdx.x * 64 + wave * 16;

  f32x4 acc[8];
  #pragma unroll
  for (int nt = 0; nt < 8; ++nt) {
    float b = bl[nt * 16 + l15];
    acc[nt] = { b, b, b, b };
  }
  #pragma unroll
  for (int kt = 0; kt < 8; ++kt) {
    const u16* ap = (kt < 4) ? (aggr  + (size_t)(rowBase + l15) * CH + kt * 32 + lg * 8)
                             : (xroot + (size_t)(rowBase + l15) * CH + (kt - 4) * 32 + lg * 8);
    bf16x8 A = *(const bf16x8*)ap;
    #pragma unroll
    for (int nt = 0; nt < 8; ++nt) {
      bf16x8 B = *(const bf16x8*)(W + (nt * 16 + l15) * 256 + kt * 32 + lg * 8);
      acc[nt] = __builtin_amdgcn_mfma_f32_16x16x32_bf16(A, B, acc[nt], 0, 0, 0);
    }
  }
  #pragma unroll
  for (int nt = 0; nt < 8; ++nt) {
    #pragma unroll
    for (int q = 0; q < 4; ++q) {
      float v = acc[nt][q];
      if (relu) v = fmaxf(v, 0.0f);
      int row = rowBase + lg * 4 + q;
      int col = nt * 16 + l15;
      if (out_bf) out_bf[(size_t)row * CH + col] = f2bf(v);
      else        out_f[(size_t)row * CH + col]  = v;
    }
  }
}

extern "C" void kernel_launch(void* const* d_in, const int* in_sizes, int n_in,
                              void* d_out, int out_size, void* d_ws, size_t ws_size,
                              hipStream_t stream) {
  (void)in_sizes; (void)n_in; (void)out_size; (void)ws_size;
  const float* x    = (const float*)d_in[0];
  const int*   ei   = (const int*)d_in[1];
  const float* w1ih = (const float*)d_in[2];
  const float* w1hh = (const float*)d_in[3];
  const float* b1ih = (const float*)d_in[4];
  const float* b1hh = (const float*)d_in[5];
  const float* w1l  = (const float*)d_in[6];
  const float* b1l  = (const float*)d_in[7];
  const float* w1r  = (const float*)d_in[8];
  const float* w2ih = (const float*)d_in[9];
  const float* w2hh = (const float*)d_in[10];
  const float* b2ih = (const float*)d_in[11];
  const float* b2hh = (const float*)d_in[12];
  const float* w2l  = (const float*)d_in[13];
  const float* b2l  = (const float*)d_in[14];
  const float* w2r  = (const float*)d_in[15];

  char* p = (char*)d_ws;
  u16* x_bf  = (u16*)p;  p += (size_t)NN * CH * 2;
  u16* h1_bf = (u16*)p;  p += (size_t)NN * CH * 2;
  u16* ag_bf = (u16*)p;  p += (size_t)NN * CH * 2;
  u16* Wc1   = (u16*)p;  p += G4 * 256 * 2;
  u16* Wc2   = (u16*)p;  p += G4 * 256 * 2;
  u16* Wl1   = (u16*)p;  p += CH * 256 * 2;
  u16* Wl2   = (u16*)p;  p += CH * 256 * 2;
  float* bs1 = (float*)p; p += G4 * 4;
  float* bs2 = (float*)p; p += G4 * 4;
  u16* Gx    = (u16*)p;  p += (size_t)NN * G4 * 2;   // 32 MB, reused by both layers

  k_cvt_bf16<<<(NN * CH / 8 + 255) / 256, 256, 0, stream>>>(x, x_bf, NN * CH / 8);
  k_pack_lstm<<<G4, 256, 0, stream>>>(w1ih, w1hh, b1ih, b1hh, Wc1, bs1);
  k_pack_lstm<<<G4, 256, 0, stream>>>(w2ih, w2hh, b2ih, b2hh, Wc2, bs2);
  k_pack_lin<<<CH, 256, 0, stream>>>(w1l, w1r, Wl1);
  k_pack_lin<<<CH, 256, 0, stream>>>(w2l, w2r, Wl2);

  k_gates<<<NN / 64, 512, 0, stream>>>(x_bf, Wc1, Gx);
  k_lstm<<<NN / MB, 512, 0, stream>>>(Gx, ei, Wc1, bs1, ag_bf);
  k_linear<<<NN / 64, 256, 0, stream>>>(ag_bf, x_bf, Wl1, b1l, h1_bf, nullptr, 1);
  k_gates<<<NN / 64, 512, 0, stream>>>(h1_bf, Wc2, Gx);
  k_lstm<<<NN / MB, 512, 0, stream>>>(Gx, ei, Wc2, bs2, ag_bf);
  k_linear<<<NN / 64, 256, 0, stream>>>(ag_bf, h1_bf, Wl2, b2l, nullptr, (float*)d_out, 0);
}